// Round 7
// baseline (878.063 us; speedup 1.0000x reference)
//
#include <hip/hip_runtime.h>
#include <hip/hip_bf16.h>
#include <cstdint>

#define IN_DIM 128
#define HID 64
#define BK 512              // nodes per bucket (power of 2)
#define BKSH 9
#define CH 4096             // edges per chunk
#define CAP 9216            // LDS csr staging capacity

typedef float f32x2 __attribute__((ext_vector_type(2)));

__device__ __forceinline__ float lrelu(float z) { return z > 0.f ? z : 0.2f * z; }

// unpack dword of 2 bf16 -> float2 {lo, hi}: 1 bit-op per feature
__device__ __forceinline__ f32x2 upk(uint32_t d) {
  f32x2 r;
  r.x = __uint_as_float(d << 16);
  r.y = __uint_as_float(d & 0xFFFF0000u);
  return r;
}

// ---------------- CSR construction (bucket counting sort) ----------------

__global__ __launch_bounds__(256) void k_bucket_hist(const int* __restrict__ dst, int E,
                                                     int* __restrict__ gcnt, int NB) {
  __shared__ int h[256];
  int tid = threadIdx.x;
  if (tid < NB) h[tid] = 0;
  __syncthreads();
  int cbase = blockIdx.x * CH;
  int cend = min(cbase + CH, E);
  for (int i = cbase + tid; i < cend; i += 256) atomicAdd(&h[dst[i] >> BKSH], 1);
  __syncthreads();
  if (tid < NB && h[tid]) atomicAdd(&gcnt[tid], h[tid]);
}

__global__ __launch_bounds__(256) void k_bucket_scan(const int* __restrict__ gcnt,
                                                     int* __restrict__ bbase,
                                                     int* __restrict__ bcur, int NB) {
  __shared__ int sc[256];
  int tid = threadIdx.x;
  int v = (tid < NB) ? gcnt[tid] : 0;
  sc[tid] = v;
  __syncthreads();
  for (int off = 1; off < 256; off <<= 1) {
    int u = (tid >= off) ? sc[tid - off] : 0;
    __syncthreads();
    sc[tid] += u;
    __syncthreads();
  }
  int excl = sc[tid] - v;
  if (tid < NB) { bbase[tid] = excl; bcur[tid] = excl; }
  if (tid == 255) bbase[NB] = sc[255];
}

__global__ __launch_bounds__(256) void k_bucket_scatter(
    const int* __restrict__ src, const int* __restrict__ dst, int E,
    int* __restrict__ bcur, uint32_t* __restrict__ staged, int NB) {
  __shared__ int h[256];
  __shared__ int base[256];
  int tid = threadIdx.x;
  if (tid < NB) h[tid] = 0;
  __syncthreads();
  int cbase = blockIdx.x * CH;
  int cend = min(cbase + CH, E);
  uint32_t pay[16];
  int bk[16], rk[16];
#pragma unroll
  for (int k = 0; k < 16; ++k) {
    int i = cbase + tid + (k << 8);
    bool valid = i < cend;
    int d = valid ? dst[i] : 0;
    int s = valid ? src[i] : 0;
    int b = d >> BKSH;
    bk[k] = valid ? b : -1;
    rk[k] = valid ? atomicAdd(&h[b], 1) : 0;
    pay[k] = (uint32_t)s | ((uint32_t)(d & (BK - 1)) << 20);
  }
  __syncthreads();
  if (tid < NB && h[tid]) base[tid] = atomicAdd(&bcur[tid], h[tid]);
  __syncthreads();
#pragma unroll
  for (int k = 0; k < 16; ++k)
    if (bk[k] >= 0) staged[base[bk[k]] + rk[k]] = pay[k];
}

__global__ __launch_bounds__(256) void k_csr_final(
    const uint32_t* __restrict__ staged, const int* __restrict__ bbase,
    int* __restrict__ offs, int* __restrict__ counts, int* __restrict__ csr, int n) {
  __shared__ int nhist[BK];
  __shared__ int sc[BK];
  __shared__ int ncur[BK];
  __shared__ int csrloc[CAP];
  int b = blockIdx.x, tid = threadIdx.x;
  int bb = bbase[b], be = bbase[b + 1];
  int cnt = be - bb;
  for (int t = tid; t < BK; t += 256) nhist[t] = 0;
  __syncthreads();
  for (int k = tid; k < cnt; k += 256) atomicAdd(&nhist[staged[bb + k] >> 20], 1);
  __syncthreads();
  sc[tid] = nhist[tid];
  sc[tid + 256] = nhist[tid + 256];
  __syncthreads();
  for (int off = 1; off < BK; off <<= 1) {
    int a0 = (tid >= off) ? sc[tid - off] : 0;
    int a1 = (tid + 256 >= off) ? sc[tid + 256 - off] : 0;
    __syncthreads();
    sc[tid] += a0;
    sc[tid + 256] += a1;
    __syncthreads();
  }
  int node0 = b << BKSH;
  for (int t = tid; t < BK; t += 256) {
    int excl = sc[t] - nhist[t];
    int node = node0 + t;
    if (node < n) { counts[node] = nhist[t]; offs[node] = bb + excl; }
    ncur[t] = excl;
  }
  __syncthreads();
  for (int k = tid; k < cnt; k += 256) {
    uint32_t u = staged[bb + k];
    int dl = u >> 20;
    int s = (int)(u & 0xFFFFFu);
    int pos = atomicAdd(&ncur[dl], 1);
    if (pos < CAP) csrloc[pos] = s;
    else csr[bb + pos] = s;
  }
  __syncthreads();
  int lim = min(cnt, CAP);
  for (int k = tid; k < lim; k += 256) csr[bb + k] = csrloc[k];
}

// ---------------- fused GEMM + attention logits (H written as bf16) -------
// X rows are wave-uniform: readfirstlane'd base so row loads broadcast
// (ideally scalarize to s_load) -- no per-fma v_readlane needed.

template <int K, int R>
__global__ __launch_bounds__(256) void k_gemm_attn(
    const float* __restrict__ X, const float* __restrict__ W,
    const float* __restrict__ As, const float* __restrict__ Ad,
    uint16_t* __restrict__ H2, float* __restrict__ LS, float* __restrict__ LD, int n) {
  int lane = threadIdx.x & 63;
  int wave = threadIdx.x >> 6;
  int row0 = (blockIdx.x * 4 + wave) * R;
  if (row0 >= n) return;
  row0 = __builtin_amdgcn_readfirstlane(row0);
  float acc[R];
#pragma unroll
  for (int r = 0; r < R; ++r) acc[r] = 0.f;

  for (int k0 = 0; k0 < K; k0 += 64) {
    float wreg[64];
#pragma unroll
    for (int kk = 0; kk < 64; ++kk) wreg[kk] = W[(size_t)(k0 + kk) * 64 + lane];
#pragma unroll
    for (int r = 0; r < R; ++r) {
      int row = row0 + r;
      if (row >= n) row = n - 1;                  // clamp (loads only)
      const float* xr = X + (size_t)row * K + k0; // wave-uniform address
#pragma unroll
      for (int kk = 0; kk < 64; ++kk)
        acc[r] = fmaf(xr[kk], wreg[kk], acc[r]);
    }
  }

  float as = As[lane], ad = Ad[lane];
#pragma unroll
  for (int r = 0; r < R; ++r) {
    int row = row0 + r;
    if (row >= n) break;
    __hip_bfloat16 hb = __float2bfloat16(acc[r]);    // RNE
    H2[((size_t)row << 6) | lane] = *(uint16_t*)&hb;
    float vs = acc[r] * as;
    float vd = acc[r] * ad;
#pragma unroll
    for (int off = 32; off; off >>= 1) {
      vs += __shfl_xor(vs, off);
      vd += __shfl_xor(vd, off);
    }
    if (lane == 0) { LS[row] = vs; LD[row] = vd; }
  }
}

// ---------------- per-node softmax aggregation ------------------------------
// One wave per node. 8 edge-groups x 8 feature-lanes.
// e-phase: 64 lanes compute w in parallel, stash (w, sidx) in an LDS pair
// buffer (invalid slots carry w=0 -> no residue handling).
// Gather: per 8-edge round, each lane: 1 ds_read_b64 (group-broadcast),
// 1 dwordx4 load (8 bf16 features), 8 bit-op unpacks, 4 pk_fma.

template <bool LAST>
__global__ __launch_bounds__(256) void k_aggregate(
    const uint16_t* __restrict__ H2, const float* __restrict__ LS, const float* __restrict__ LD,
    const int* __restrict__ csr, const int* __restrict__ offs, const int* __restrict__ counts,
    const float* __restrict__ b, float* __restrict__ Out, int n) {
  __shared__ uint2 pairbuf[4][64];
  int lane = threadIdx.x & 63;
  int wid = threadIdx.x >> 6;
  int node = blockIdx.x * 4 + wid;
  if (node >= n) return;
  int q = lane & 7;         // feature octet: features 8q..8q+7
  int g = lane >> 3;        // edge group 0..7
  int start = offs[node];
  int deg = counts[node];
  const uint4* h2q = (const uint4*)H2;      // row = 8 x 16B granules
  float ldv = LD[node];
  float m = lrelu(LS[node] + ldv);          // e_self (running max)
  float ssum_l = (lane == 0) ? 1.f : 0.f;

  f32x2 a01 = {0.f, 0.f}, a23 = {0.f, 0.f}, a45 = {0.f, 0.f}, a67 = {0.f, 0.f};

  // self round (w = 1), only group 0 contributes
  {
    uint4 u = h2q[((uint32_t)node << 3) + q];
    float ws = (g == 0) ? 1.f : 0.f;
    f32x2 w2 = {ws, ws};
    a01 += w2 * upk(u.x);
    a23 += w2 * upk(u.y);
    a45 += w2 * upk(u.z);
    a67 += w2 * upk(u.w);
  }

  for (int c = 0; c < deg; c += 64) {
    int j = c + lane;
    bool valid = j < deg;
    int sidx = csr[start + (valid ? j : 0)];
    float e = valid ? lrelu(LS[sidx] + ldv) : -1e30f;
    float cm = e;
#pragma unroll
    for (int off = 32; off; off >>= 1) cm = fmaxf(cm, __shfl_xor(cm, off));
    if (cm > m) {
      float s = __expf(m - cm);
      f32x2 s2 = {s, s};
      a01 *= s2; a23 *= s2; a45 *= s2; a67 *= s2;
      ssum_l *= s;
      m = cm;
    }
    float w = valid ? __expf(e - m) : 0.f;   // invalid slots: w = 0
    ssum_l += w;
    pairbuf[wid][lane] = make_uint2(__float_as_uint(w), (uint32_t)sidx);
    int nn = min(64, deg - c);
#pragma unroll 2
    for (int jj = 0; jj < nn; jj += 8) {
      uint2 pr = pairbuf[wid][jj + g];       // broadcast within 8-lane group
      float we = __uint_as_float(pr.x);
      uint4 u = h2q[(pr.y << 3) + q];
      f32x2 w2 = {we, we};
      a01 += w2 * upk(u.x);
      a23 += w2 * upk(u.y);
      a45 += w2 * upk(u.z);
      a67 += w2 * upk(u.w);
    }
  }

  // combine the 8 edge-groups (xor butterfly; every lane gets full sums)
#pragma unroll
  for (int off = 8; off <= 32; off <<= 1) {
    a01.x += __shfl_xor(a01.x, off); a01.y += __shfl_xor(a01.y, off);
    a23.x += __shfl_xor(a23.x, off); a23.y += __shfl_xor(a23.y, off);
    a45.x += __shfl_xor(a45.x, off); a45.y += __shfl_xor(a45.y, off);
    a67.x += __shfl_xor(a67.x, off); a67.y += __shfl_xor(a67.y, off);
  }
  float ssum = ssum_l;
#pragma unroll
  for (int off = 32; off; off >>= 1) ssum += __shfl_xor(ssum, off);
  float inv = 1.f / ssum;
  const f32x2* b2 = (const f32x2*)b;
  f32x2 i2 = {inv, inv};
  f32x2 v01 = a01 * i2 + b2[4 * q + 0];
  f32x2 v23 = a23 * i2 + b2[4 * q + 1];
  f32x2 v45 = a45 * i2 + b2[4 * q + 2];
  f32x2 v67 = a67 * i2 + b2[4 * q + 3];
  v01.x = fmaxf(v01.x, 0.f); v01.y = fmaxf(v01.y, 0.f);
  v23.x = fmaxf(v23.x, 0.f); v23.y = fmaxf(v23.y, 0.f);
  v45.x = fmaxf(v45.x, 0.f); v45.y = fmaxf(v45.y, 0.f);
  v67.x = fmaxf(v67.x, 0.f); v67.y = fmaxf(v67.y, 0.f);
  if (LAST) {
    float mx = fmaxf(fmaxf(fmaxf(v01.x, v01.y), fmaxf(v23.x, v23.y)),
                     fmaxf(fmaxf(v45.x, v45.y), fmaxf(v67.x, v67.y)));
#pragma unroll
    for (int off = 1; off <= 4; off <<= 1) mx = fmaxf(mx, __shfl_xor(mx, off));
    float ex = __expf(v01.x - mx) + __expf(v01.y - mx) + __expf(v23.x - mx) +
               __expf(v23.y - mx) + __expf(v45.x - mx) + __expf(v45.y - mx) +
               __expf(v67.x - mx) + __expf(v67.y - mx);
#pragma unroll
    for (int off = 1; off <= 4; off <<= 1) ex += __shfl_xor(ex, off);
    float lse = mx + logf(ex);
    v01.x -= lse; v01.y -= lse; v23.x -= lse; v23.y -= lse;
    v45.x -= lse; v45.y -= lse; v67.x -= lse; v67.y -= lse;
  }
  if (g < 2) {
    float4 o = (g == 0) ? make_float4(v01.x, v01.y, v23.x, v23.y)
                        : make_float4(v45.x, v45.y, v67.x, v67.y);
    ((float4*)(Out + ((size_t)node << 6)))[2 * q + g] = o;
  }
}

// ---------------- launcher ----------------

extern "C" void kernel_launch(void* const* d_in, const int* in_sizes, int n_in,
                              void* d_out, int out_size, void* d_ws, size_t ws_size,
                              hipStream_t stream) {
  const float* x = (const float*)d_in[0];
  const int* ei = (const int*)d_in[1];
  const int N = in_sizes[0] / IN_DIM;       // 100000
  const int E = in_sizes[1] / 2;            // 1600000
  const int* src = ei;
  const int* dst = ei + E;
  const int NB = (N + BK - 1) >> BKSH;      // 196

  const float *W[6], *As[6], *Ad[6], *Bb[6];
  for (int i = 0; i < 6; ++i) {
    W[i]  = (const float*)d_in[3 + 4 * i];
    As[i] = (const float*)d_in[4 + 4 * i];
    Ad[i] = (const float*)d_in[5 + 4 * i];
    Bb[i] = (const float*)d_in[6 + 4 * i];
  }

  char* p = (char*)d_ws;
  auto alloc = [&](size_t bytes) -> void* {
    void* r = (void*)p;
    p += (bytes + 255) & ~(size_t)255;
    return r;
  };
  int* counts  = (int*)alloc((size_t)N * 4);
  int* offs    = (int*)alloc((size_t)N * 4);
  int* gcnt    = (int*)alloc((size_t)NB * 4);
  int* bbase   = (int*)alloc((size_t)(NB + 1) * 4);
  int* bcur    = (int*)alloc((size_t)NB * 4);
  int* csr     = (int*)alloc((size_t)E * 4);
  float* ls    = (float*)alloc((size_t)N * 4);
  float* ld    = (float*)alloc((size_t)N * 4);
  uint16_t* h2 = (uint16_t*)alloc((size_t)N * HID * 2);
  float* F0    = (float*)alloc((size_t)N * HID * 4);
  float* F1    = (float*)d_out;
  uint32_t* staged = (uint32_t*)F0;          // alias: dead before first aggregate

  // ---- CSR build ----
  int NC = (E + CH - 1) / CH;
  hipMemsetAsync(gcnt, 0, (size_t)NB * 4, stream);
  k_bucket_hist<<<NC, 256, 0, stream>>>(dst, E, gcnt, NB);
  k_bucket_scan<<<1, 256, 0, stream>>>(gcnt, bbase, bcur, NB);
  k_bucket_scatter<<<NC, 256, 0, stream>>>(src, dst, E, bcur, staged, NB);
  k_csr_final<<<NB, 256, 0, stream>>>(staged, bbase, offs, counts, csr, N);

  // ---- 6 GAT layers ----
  const int R = 8;
  int gemm_grid = (N + 4 * R - 1) / (4 * R);    // 3125
  int node_grid = (N + 3) / 4;                  // 25000
  const float* fin = x;
  float* fbuf[2] = {F0, F1};
  for (int L = 0; L < 6; ++L) {
    if (L == 0)
      k_gemm_attn<IN_DIM, R><<<gemm_grid, 256, 0, stream>>>(fin, W[L], As[L], Ad[L],
                                                            h2, ls, ld, N);
    else
      k_gemm_attn<HID, R><<<gemm_grid, 256, 0, stream>>>(fin, W[L], As[L], Ad[L],
                                                         h2, ls, ld, N);
    float* fout = fbuf[L & 1];
    if (L == 5)
      k_aggregate<true><<<node_grid, 256, 0, stream>>>(h2, ls, ld, csr, offs, counts,
                                                       Bb[L], fout, N);
    else
      k_aggregate<false><<<node_grid, 256, 0, stream>>>(h2, ls, ld, csr, offs, counts,
                                                        Bb[L], fout, N);
    fin = fout;
  }
}

// Round 8
// 620.480 us; speedup vs baseline: 1.4151x; 1.4151x over previous
//
#include <hip/hip_runtime.h>
#include <hip/hip_bf16.h>
#include <cstdint>

#define IN_DIM 128
#define HID 64
#define BK 512              // nodes per bucket (power of 2)
#define BKSH 9
#define CH 4096             // edges per chunk
#define CAP 9216            // LDS csr staging capacity

typedef float f32x2 __attribute__((ext_vector_type(2)));
typedef float f32x4 __attribute__((ext_vector_type(4)));
typedef short s16x8 __attribute__((ext_vector_type(8)));   // 8 bf16 (4 VGPRs)

__device__ __forceinline__ float lrelu(float z) { return z > 0.f ? z : 0.2f * z; }

// unpack dword of 2 bf16 -> float2 {lo, hi}: 1 bit-op per feature
__device__ __forceinline__ f32x2 upk(uint32_t d) {
  f32x2 r;
  r.x = __uint_as_float(d << 16);
  r.y = __uint_as_float(d & 0xFFFF0000u);
  return r;
}

__device__ __forceinline__ uint16_t f2b(float f) {
  __hip_bfloat16 h = __float2bfloat16(f);          // RNE
  return *(uint16_t*)&h;
}
__device__ __forceinline__ uint32_t pk2(float a, float b) {
  return (uint32_t)f2b(a) | ((uint32_t)f2b(b) << 16);
}

// ---------------- input prep: x -> bf16, W -> bf16 transposed ----------------

__global__ __launch_bounds__(256) void k_xprep(const float* __restrict__ x,
                                               uint16_t* __restrict__ xb, int total8) {
  int gid = blockIdx.x * 256 + threadIdx.x;
  if (gid >= total8) return;
  const float4* xp = (const float4*)x;
  float4 u = xp[2 * gid], v = xp[2 * gid + 1];
  uint4 o;
  o.x = pk2(u.x, u.y); o.y = pk2(u.z, u.w);
  o.z = pk2(v.x, v.y); o.w = pk2(v.z, v.w);
  ((uint4*)xb)[gid] = o;
}

// Wt layout: [col][k] bf16; layer0 at 0 (64x128), layer L at 8192+(L-1)*4096
__global__ __launch_bounds__(256) void k_wprep(
    const float* __restrict__ w0, const float* __restrict__ w1,
    const float* __restrict__ w2, const float* __restrict__ w3,
    const float* __restrict__ w4, const float* __restrict__ w5,
    uint16_t* __restrict__ wt) {
  int gid = blockIdx.x * 256 + threadIdx.x;    // 0 .. 28671
  const float* W; int c, k, off;
  if (gid < 8192) { W = w0; c = gid >> 7; k = gid & 127; off = gid; }
  else {
    int idx = gid - 8192;
    int L = idx >> 12;                         // 0..4 -> layers 1..5
    int local = idx & 4095;
    const float* ws[5] = {w1, w2, w3, w4, w5};
    W = ws[L]; c = local >> 6; k = local & 63; off = 8192 + L * 4096 + local;
  }
  wt[off] = f2b(W[k * 64 + c]);
}

// ---------------- CSR construction (bucket counting sort) ----------------

__global__ __launch_bounds__(256) void k_bucket_hist(const int* __restrict__ dst, int E,
                                                     int* __restrict__ gcnt, int NB) {
  __shared__ int h[256];
  int tid = threadIdx.x;
  if (tid < NB) h[tid] = 0;
  __syncthreads();
  int cbase = blockIdx.x * CH;
  int cend = min(cbase + CH, E);
  for (int i = cbase + tid; i < cend; i += 256) atomicAdd(&h[dst[i] >> BKSH], 1);
  __syncthreads();
  if (tid < NB && h[tid]) atomicAdd(&gcnt[tid], h[tid]);
}

__global__ __launch_bounds__(256) void k_bucket_scan(const int* __restrict__ gcnt,
                                                     int* __restrict__ bbase,
                                                     int* __restrict__ bcur, int NB) {
  __shared__ int sc[256];
  int tid = threadIdx.x;
  int v = (tid < NB) ? gcnt[tid] : 0;
  sc[tid] = v;
  __syncthreads();
  for (int off = 1; off < 256; off <<= 1) {
    int u = (tid >= off) ? sc[tid - off] : 0;
    __syncthreads();
    sc[tid] += u;
    __syncthreads();
  }
  int excl = sc[tid] - v;
  if (tid < NB) { bbase[tid] = excl; bcur[tid] = excl; }
  if (tid == 255) bbase[NB] = sc[255];
}

__global__ __launch_bounds__(256) void k_bucket_scatter(
    const int* __restrict__ src, const int* __restrict__ dst, int E,
    int* __restrict__ bcur, uint32_t* __restrict__ staged, int NB) {
  __shared__ int h[256];
  __shared__ int base[256];
  int tid = threadIdx.x;
  if (tid < NB) h[tid] = 0;
  __syncthreads();
  int cbase = blockIdx.x * CH;
  int cend = min(cbase + CH, E);
  uint32_t pay[16];
  int bk[16], rk[16];
#pragma unroll
  for (int k = 0; k < 16; ++k) {
    int i = cbase + tid + (k << 8);
    bool valid = i < cend;
    int d = valid ? dst[i] : 0;
    int s = valid ? src[i] : 0;
    int b = d >> BKSH;
    bk[k] = valid ? b : -1;
    rk[k] = valid ? atomicAdd(&h[b], 1) : 0;
    pay[k] = (uint32_t)s | ((uint32_t)(d & (BK - 1)) << 20);
  }
  __syncthreads();
  if (tid < NB && h[tid]) base[tid] = atomicAdd(&bcur[tid], h[tid]);
  __syncthreads();
#pragma unroll
  for (int k = 0; k < 16; ++k)
    if (bk[k] >= 0) staged[base[bk[k]] + rk[k]] = pay[k];
}

__global__ __launch_bounds__(256) void k_csr_final(
    const uint32_t* __restrict__ staged, const int* __restrict__ bbase,
    int* __restrict__ offs, int* __restrict__ counts, int* __restrict__ csr, int n) {
  __shared__ int nhist[BK];
  __shared__ int sc[BK];
  __shared__ int ncur[BK];
  __shared__ int csrloc[CAP];
  int b = blockIdx.x, tid = threadIdx.x;
  int bb = bbase[b], be = bbase[b + 1];
  int cnt = be - bb;
  for (int t = tid; t < BK; t += 256) nhist[t] = 0;
  __syncthreads();
  for (int k = tid; k < cnt; k += 256) atomicAdd(&nhist[staged[bb + k] >> 20], 1);
  __syncthreads();
  sc[tid] = nhist[tid];
  sc[tid + 256] = nhist[tid + 256];
  __syncthreads();
  for (int off = 1; off < BK; off <<= 1) {
    int a0 = (tid >= off) ? sc[tid - off] : 0;
    int a1 = (tid + 256 >= off) ? sc[tid + 256 - off] : 0;
    __syncthreads();
    sc[tid] += a0;
    sc[tid + 256] += a1;
    __syncthreads();
  }
  int node0 = b << BKSH;
  for (int t = tid; t < BK; t += 256) {
    int excl = sc[t] - nhist[t];
    int node = node0 + t;
    if (node < n) { counts[node] = nhist[t]; offs[node] = bb + excl; }
    ncur[t] = excl;
  }
  __syncthreads();
  for (int k = tid; k < cnt; k += 256) {
    uint32_t u = staged[bb + k];
    int dl = u >> 20;
    int s = (int)(u & 0xFFFFFu);
    int pos = atomicAdd(&ncur[dl], 1);
    if (pos < CAP) csrloc[pos] = s;
    else csr[bb + pos] = s;
  }
  __syncthreads();
  int lim = min(cnt, CAP);
  for (int k = tid; k < lim; k += 256) csr[bb + k] = csrloc[k];
}

// ---------------- MFMA GEMM + attention logits ----------------
// Wave computes 32 rows x 64 cols. A: bf16 features [n][K]; B: Wt [64][K].
// Frag layouts (m89-verified): A row=l&15, k=(l>>4)*8+j; B col=l&15, same k;
// C/D col=l&15, row=(l>>4)*4+reg. ls/ld from fp32 acc (full precision).

template <int K>
__global__ __launch_bounds__(256) void k_gemm_mfma(
    const uint16_t* __restrict__ Xb, const uint16_t* __restrict__ Wt,
    const float* __restrict__ As, const float* __restrict__ Ad,
    uint16_t* __restrict__ H2, float* __restrict__ LS, float* __restrict__ LD, int n) {
  int lane = threadIdx.x & 63;
  int wave = threadIdx.x >> 6;
  int row0 = (blockIdx.x * 4 + wave) * 32;
  if (row0 >= n) return;
  int lr = lane & 15;
  int lk = lane >> 4;

  f32x4 acc[2][4];
#pragma unroll
  for (int mt = 0; mt < 2; ++mt)
#pragma unroll
    for (int f = 0; f < 4; ++f) acc[mt][f] = (f32x4)0.f;

#pragma unroll
  for (int ks = 0; ks < K / 32; ++ks) {
    s16x8 a[2];
#pragma unroll
    for (int mt = 0; mt < 2; ++mt) {
      int m = row0 + mt * 16 + lr;
      if (m >= n) m = n - 1;                     // clamp (loads only)
      a[mt] = *(const s16x8*)&Xb[(size_t)m * K + ks * 32 + lk * 8];
    }
#pragma unroll
    for (int f = 0; f < 4; ++f) {
      s16x8 bfr = *(const s16x8*)&Wt[(size_t)(f * 16 + lr) * K + ks * 32 + lk * 8];
      acc[0][f] = __builtin_amdgcn_mfma_f32_16x16x32_bf16(a[0], bfr, acc[0][f], 0, 0, 0);
      acc[1][f] = __builtin_amdgcn_mfma_f32_16x16x32_bf16(a[1], bfr, acc[1][f], 0, 0, 0);
    }
  }

  float as4[4], ad4[4];
#pragma unroll
  for (int f = 0; f < 4; ++f) { as4[f] = As[f * 16 + lr]; ad4[f] = Ad[f * 16 + lr]; }

#pragma unroll
  for (int mt = 0; mt < 2; ++mt) {
#pragma unroll
    for (int r = 0; r < 4; ++r) {
      int row = row0 + mt * 16 + lk * 4 + r;
      bool ok = row < n;
      float vs = 0.f, vd = 0.f;
#pragma unroll
      for (int f = 0; f < 4; ++f) {
        float v = acc[mt][f][r];
        if (ok) H2[(size_t)row * 64 + f * 16 + lr] = f2b(v);
        vs = fmaf(v, as4[f], vs);
        vd = fmaf(v, ad4[f], vd);
      }
#pragma unroll
      for (int off = 1; off < 16; off <<= 1) {
        vs += __shfl_xor(vs, off);
        vd += __shfl_xor(vd, off);
      }
      if (ok && lr == 0) { LS[row] = vs; LD[row] = vd; }
    }
  }
}

// ---------------- per-node softmax aggregation (LDS pairbuf, bf16 out) -----

template <bool LAST>
__global__ __launch_bounds__(256) void k_aggregate(
    const uint16_t* __restrict__ H2, const float* __restrict__ LS, const float* __restrict__ LD,
    const int* __restrict__ csr, const int* __restrict__ offs, const int* __restrict__ counts,
    const float* __restrict__ b, float* __restrict__ OutF, uint16_t* __restrict__ OutB, int n) {
  __shared__ uint2 pairbuf[4][64];
  int lane = threadIdx.x & 63;
  int wid = threadIdx.x >> 6;
  int node = blockIdx.x * 4 + wid;
  if (node >= n) return;
  int q = lane & 7;         // feature octet: features 8q..8q+7
  int g = lane >> 3;        // edge group 0..7
  int start = offs[node];
  int deg = counts[node];
  const uint4* h2q = (const uint4*)H2;
  float ldv = LD[node];
  float m = lrelu(LS[node] + ldv);
  float ssum_l = (lane == 0) ? 1.f : 0.f;

  f32x2 a01 = {0.f, 0.f}, a23 = {0.f, 0.f}, a45 = {0.f, 0.f}, a67 = {0.f, 0.f};

  {
    uint4 u = h2q[((uint32_t)node << 3) + q];
    float ws = (g == 0) ? 1.f : 0.f;
    f32x2 w2 = {ws, ws};
    a01 += w2 * upk(u.x);
    a23 += w2 * upk(u.y);
    a45 += w2 * upk(u.z);
    a67 += w2 * upk(u.w);
  }

  for (int c = 0; c < deg; c += 64) {
    int j = c + lane;
    bool valid = j < deg;
    int sidx = csr[start + (valid ? j : 0)];
    float e = valid ? lrelu(LS[sidx] + ldv) : -1e30f;
    float cm = e;
#pragma unroll
    for (int off = 32; off; off >>= 1) cm = fmaxf(cm, __shfl_xor(cm, off));
    if (cm > m) {
      float s = __expf(m - cm);
      f32x2 s2 = {s, s};
      a01 *= s2; a23 *= s2; a45 *= s2; a67 *= s2;
      ssum_l *= s;
      m = cm;
    }
    float w = valid ? __expf(e - m) : 0.f;
    ssum_l += w;
    pairbuf[wid][lane] = make_uint2(__float_as_uint(w), (uint32_t)sidx);
    int nn = min(64, deg - c);
#pragma unroll 2
    for (int jj = 0; jj < nn; jj += 8) {
      uint2 pr = pairbuf[wid][jj + g];
      float we = __uint_as_float(pr.x);
      uint4 u = h2q[(pr.y << 3) + q];
      f32x2 w2 = {we, we};
      a01 += w2 * upk(u.x);
      a23 += w2 * upk(u.y);
      a45 += w2 * upk(u.z);
      a67 += w2 * upk(u.w);
    }
  }

#pragma unroll
  for (int off = 8; off <= 32; off <<= 1) {
    a01.x += __shfl_xor(a01.x, off); a01.y += __shfl_xor(a01.y, off);
    a23.x += __shfl_xor(a23.x, off); a23.y += __shfl_xor(a23.y, off);
    a45.x += __shfl_xor(a45.x, off); a45.y += __shfl_xor(a45.y, off);
    a67.x += __shfl_xor(a67.x, off); a67.y += __shfl_xor(a67.y, off);
  }
  float ssum = ssum_l;
#pragma unroll
  for (int off = 32; off; off >>= 1) ssum += __shfl_xor(ssum, off);
  float inv = 1.f / ssum;
  const f32x2* b2 = (const f32x2*)b;
  f32x2 i2 = {inv, inv};
  f32x2 v01 = a01 * i2 + b2[4 * q + 0];
  f32x2 v23 = a23 * i2 + b2[4 * q + 1];
  f32x2 v45 = a45 * i2 + b2[4 * q + 2];
  f32x2 v67 = a67 * i2 + b2[4 * q + 3];
  v01.x = fmaxf(v01.x, 0.f); v01.y = fmaxf(v01.y, 0.f);
  v23.x = fmaxf(v23.x, 0.f); v23.y = fmaxf(v23.y, 0.f);
  v45.x = fmaxf(v45.x, 0.f); v45.y = fmaxf(v45.y, 0.f);
  v67.x = fmaxf(v67.x, 0.f); v67.y = fmaxf(v67.y, 0.f);
  if (LAST) {
    float mx = fmaxf(fmaxf(fmaxf(v01.x, v01.y), fmaxf(v23.x, v23.y)),
                     fmaxf(fmaxf(v45.x, v45.y), fmaxf(v67.x, v67.y)));
#pragma unroll
    for (int off = 1; off <= 4; off <<= 1) mx = fmaxf(mx, __shfl_xor(mx, off));
    float ex = __expf(v01.x - mx) + __expf(v01.y - mx) + __expf(v23.x - mx) +
               __expf(v23.y - mx) + __expf(v45.x - mx) + __expf(v45.y - mx) +
               __expf(v67.x - mx) + __expf(v67.y - mx);
#pragma unroll
    for (int off = 1; off <= 4; off <<= 1) ex += __shfl_xor(ex, off);
    float lse = mx + logf(ex);
    if (g < 2) {
      float4 o = (g == 0) ? make_float4(v01.x - lse, v01.y - lse, v23.x - lse, v23.y - lse)
                          : make_float4(v45.x - lse, v45.y - lse, v67.x - lse, v67.y - lse);
      ((float4*)(OutF + ((size_t)node << 6)))[2 * q + g] = o;
    }
  } else {
    if (g == 0) {
      uint4 o;
      o.x = pk2(v01.x, v01.y); o.y = pk2(v23.x, v23.y);
      o.z = pk2(v45.x, v45.y); o.w = pk2(v67.x, v67.y);
      ((uint4*)(OutB + ((size_t)node << 6)))[q] = o;
    }
  }
}

// ---------------- launcher ----------------

extern "C" void kernel_launch(void* const* d_in, const int* in_sizes, int n_in,
                              void* d_out, int out_size, void* d_ws, size_t ws_size,
                              hipStream_t stream) {
  const float* x = (const float*)d_in[0];
  const int* ei = (const int*)d_in[1];
  const int N = in_sizes[0] / IN_DIM;       // 100000
  const int E = in_sizes[1] / 2;            // 1600000
  const int* src = ei;
  const int* dst = ei + E;
  const int NB = (N + BK - 1) >> BKSH;      // 196

  const float *W[6], *As[6], *Ad[6], *Bb[6];
  for (int i = 0; i < 6; ++i) {
    W[i]  = (const float*)d_in[3 + 4 * i];
    As[i] = (const float*)d_in[4 + 4 * i];
    Ad[i] = (const float*)d_in[5 + 4 * i];
    Bb[i] = (const float*)d_in[6 + 4 * i];
  }

  char* p = (char*)d_ws;
  auto alloc = [&](size_t bytes) -> void* {
    void* r = (void*)p;
    p += (bytes + 255) & ~(size_t)255;
    return r;
  };
  int* counts  = (int*)alloc((size_t)N * 4);
  int* offs    = (int*)alloc((size_t)N * 4);
  int* gcnt    = (int*)alloc((size_t)NB * 4);
  int* bbase   = (int*)alloc((size_t)(NB + 1) * 4);
  int* bcur    = (int*)alloc((size_t)NB * 4);
  int* csr     = (int*)alloc((size_t)E * 4);
  float* ls    = (float*)alloc((size_t)N * 4);
  float* ld    = (float*)alloc((size_t)N * 4);
  uint16_t* h2 = (uint16_t*)alloc((size_t)N * HID * 2);
  uint16_t* xb = (uint16_t*)alloc((size_t)N * IN_DIM * 2);
  uint16_t* fb = (uint16_t*)alloc((size_t)N * HID * 2);
  uint16_t* wt = (uint16_t*)alloc((size_t)28672 * 2);
  uint32_t* staged = (uint32_t*)fb;     // alias: fb dead until first aggregate

  // ---- prep: bf16 conversions ----
  k_xprep<<<(N * IN_DIM / 8 + 255) / 256, 256, 0, stream>>>(x, xb, N * IN_DIM / 8);
  k_wprep<<<112, 256, 0, stream>>>(W[0], W[1], W[2], W[3], W[4], W[5], wt);

  // ---- CSR build ----
  int NC = (E + CH - 1) / CH;
  hipMemsetAsync(gcnt, 0, (size_t)NB * 4, stream);
  k_bucket_hist<<<NC, 256, 0, stream>>>(dst, E, gcnt, NB);
  k_bucket_scan<<<1, 256, 0, stream>>>(gcnt, bbase, bcur, NB);
  k_bucket_scatter<<<NC, 256, 0, stream>>>(src, dst, E, bcur, staged, NB);
  k_csr_final<<<NB, 256, 0, stream>>>(staged, bbase, offs, counts, csr, N);

  // ---- 6 GAT layers ----
  int gemm_grid = (N + 127) / 128;              // 782
  int node_grid = (N + 3) / 4;                  // 25000
  const uint16_t* wt_off[6];
  wt_off[0] = wt;
  for (int L = 1; L < 6; ++L) wt_off[L] = wt + 8192 + (L - 1) * 4096;

  for (int L = 0; L < 6; ++L) {
    if (L == 0)
      k_gemm_mfma<IN_DIM><<<gemm_grid, 256, 0, stream>>>(xb, wt_off[0], As[0], Ad[0],
                                                         h2, ls, ld, N);
    else
      k_gemm_mfma<HID><<<gemm_grid, 256, 0, stream>>>(fb, wt_off[L], As[L], Ad[L],
                                                      h2, ls, ld, N);
    if (L == 5)
      k_aggregate<true><<<node_grid, 256, 0, stream>>>(h2, ls, ld, csr, offs, counts,
                                                       Bb[L], (float*)d_out, nullptr, N);
    else
      k_aggregate<false><<<node_grid, 256, 0, stream>>>(h2, ls, ld, csr, offs, counts,
                                                        Bb[L], nullptr, fb, N);
  }
}